// Round 7
// baseline (326.317 us; speedup 1.0000x reference)
//
#include <hip/hip_runtime.h>
#include <hip/hip_bf16.h>
#include <stdint.h>
#include <stddef.h>

// ---------- types ----------
typedef __bf16 bf16x8 __attribute__((ext_vector_type(8)));
typedef float  f32x16 __attribute__((ext_vector_type(16)));

// ---------- helpers ----------
__device__ __forceinline__ float fp8e4m3_to_f32(uint32_t b) {
    uint32_t e = (b >> 3) & 15u, m = b & 7u;
    float mag;
    if (e == 0)
        mag = (float)m * (1.0f / 512.0f);
    else
        mag = __uint_as_float(((e + 120u) << 23) | (m << 20));
    return (b & 0x80u) ? -mag : mag;
}

__device__ __forceinline__ unsigned short f32_to_bf16_bits(float f) {
    uint32_t x = __float_as_uint(f);
    uint32_t r = x + 0x7fffu + ((x >> 16) & 1u);   // RNE
    return (unsigned short)(r >> 16);
}

__device__ __forceinline__ void gload_lds16(const void* g, void* l) {
    __builtin_amdgcn_global_load_lds(
        (const __attribute__((address_space(1))) uint32_t*)g,
        (__attribute__((address_space(3))) uint32_t*)l,
        16, 0, 0);
}

// ---------- dtype detector (3-way), validated round 3 (mode 0 = f32) ----------
__global__ void detect_kernel(const uint32_t* __restrict__ w,
                              uint32_t* __restrict__ flag) {
    __shared__ int sF, sB;
    if (threadIdx.x == 0) { sF = 1; sB = 1; }
    __syncthreads();
    int f32ok = 1, bf16ok = 1;
    #pragma unroll
    for (int i = 0; i < 16; ++i) {
        uint32_t u = w[threadIdx.x * 16 + i];
        if (u & 0x000FFFFFu) f32ok = 0;
        if (u & 0x000F000Fu) bf16ok = 0;
    }
    if (!f32ok)  atomicExch(&sF, 0);
    if (!bf16ok) atomicExch(&sB, 0);
    __syncthreads();
    if (threadIdx.x == 0)
        *flag = sF ? 0u : (sB ? 1u : 2u);
}

// ---------- pre-pass 1: x f32 -> bf16 ----------
__global__ void cvt_x_kernel(const float* __restrict__ x,
                             unsigned short* __restrict__ out, size_t n8) {
    size_t stride = (size_t)gridDim.x * blockDim.x;
    for (size_t i = (size_t)blockIdx.x * blockDim.x + threadIdx.x; i < n8; i += stride) {
        const float4* p = (const float4*)(x + i * 8);
        float4 a = p[0], b = p[1];
        union { uint4 v; unsigned short s[8]; } o;
        o.s[0] = f32_to_bf16_bits(a.x); o.s[1] = f32_to_bf16_bits(a.y);
        o.s[2] = f32_to_bf16_bits(a.z); o.s[3] = f32_to_bf16_bits(a.w);
        o.s[4] = f32_to_bf16_bits(b.x); o.s[5] = f32_to_bf16_bits(b.y);
        o.s[6] = f32_to_bf16_bits(b.z); o.s[7] = f32_to_bf16_bits(b.w);
        *(uint4*)(out + i * 8) = o.v;
    }
}

// ---------- pre-pass 2: weight (any mode) -> canonical bf16 ----------
__global__ void prep_w_kernel(const void* __restrict__ wsrc,
                              const uint32_t* __restrict__ flag,
                              unsigned short* __restrict__ out, size_t n8) {
    const uint32_t mode = *flag;
    size_t stride = (size_t)gridDim.x * blockDim.x;
    for (size_t i = (size_t)blockIdx.x * blockDim.x + threadIdx.x; i < n8; i += stride) {
        union { uint4 v; unsigned short s[8]; } o;
        if (mode == 0) {
            const float4* p = (const float4*)((const float*)wsrc + i * 8);
            float4 a = p[0], b = p[1];
            o.s[0] = f32_to_bf16_bits(a.x); o.s[1] = f32_to_bf16_bits(a.y);
            o.s[2] = f32_to_bf16_bits(a.z); o.s[3] = f32_to_bf16_bits(a.w);
            o.s[4] = f32_to_bf16_bits(b.x); o.s[5] = f32_to_bf16_bits(b.y);
            o.s[6] = f32_to_bf16_bits(b.z); o.s[7] = f32_to_bf16_bits(b.w);
        } else if (mode == 1) {
            o.v = *(const uint4*)((const unsigned short*)wsrc + i * 8);
        } else {
            union { uint2 v; uint8_t b[8]; } u;
            u.v = *(const uint2*)((const uint8_t*)wsrc + i * 8);
            #pragma unroll
            for (int j = 0; j < 8; ++j)
                o.s[j] = f32_to_bf16_bits(fp8e4m3_to_f32(u.b[j]));
        }
        *(uint4*)(out + i * 8) = o.v;
    }
}

// ================= 256x256 8-phase GEMM, 32x32x16 MFMA ======================
// Round-7 delta vs round-6 (schedule/staging/swizzle UNCHANGED): MFMA shape
// 16x16x32 -> 32x32x16 (measured ceiling 2075 -> 2382-2495 TF, and halves
// MFMA instruction count). Per wave: 4 Mtiles x 2 Ntiles of 32x32, K=64 as
// 4 ksteps of 16. Fragment maps:
//   A: row=lane&31, k=(lane>>5)*8+j  (analog of proven 16x16 map; k-map
//      self-cancels between A and B)
//   B: col(W-row)=lane&31, same k map
//   C/D: col=lane&31, row=(reg&3)+8*(reg>>2)+4*(lane>>5)  [m74/m101]
// ds_read count unchanged: 24 b128/wave/K-tile; quarter-wave bank aliasing
// stays <=2-way (free).

#define GBM 256
#define GBN 256
#define GBK 64

#define PH_IN() do {                                                           \
    __builtin_amdgcn_s_barrier();                                              \
    __builtin_amdgcn_s_setprio(1);                                             \
} while (0)

#define PH_OUT() do {                                                          \
    __builtin_amdgcn_s_setprio(0);                                             \
    __builtin_amdgcn_s_barrier();                                              \
} while (0)

// A fragments for one qm (2 Mtiles x 4 ksteps); offsets aoffK[ks]+mt*4096
#define LDA_(qm) do {                                                          \
    _Pragma("unroll") for (int mt = 0; mt < 2; ++mt)                           \
    _Pragma("unroll") for (int ks = 0; ks < 4; ++ks)                           \
        Af[mt][ks] = *(const bf16x8*)(ldsA + aoffK[ks] + ((qm)*2+mt)*4096);    \
} while (0)

// B fragments for one nt (4 ksteps)
#define LDB_(nt, Bf) do {                                                      \
    _Pragma("unroll") for (int ks = 0; ks < 4; ++ks)                           \
        Bf[ks] = *(const bf16x8*)(ldsB + boffK[ks] + (nt)*4096);               \
} while (0)

// 8 MFMA: ks outer so adjacent MFMAs target different acc (dep distance 2)
#define MFMA_(qm, nt, Bf) do {                                                 \
    _Pragma("unroll") for (int ks = 0; ks < 4; ++ks)                           \
    _Pragma("unroll") for (int mt = 0; mt < 2; ++mt)                           \
        acc[(qm)*2+mt][nt] = __builtin_amdgcn_mfma_f32_32x32x16_bf16(          \
            Af[mt][ks], Bf[ks], acc[(qm)*2+mt][nt], 0, 0, 0);                  \
} while (0)

// stage one 256x64 tile (4 x gload_lds16 per thread)
#define STAGE_(gsrc, koff, ldst) do {                                          \
    const uint8_t* _p = (gsrc) + (koff);                                       \
    _Pragma("unroll") for (int j = 0; j < 4; ++j)                              \
        gload_lds16(_p + (size_t)j * 64 * KB2, (ldst) + (sdst + j*8192));      \
} while (0)

__global__ __launch_bounds__(512, 2)
void gemm256_8ph(const unsigned short* __restrict__ A,
                 const unsigned short* __restrict__ Bw,
                 const float* __restrict__ invp,
                 const float* __restrict__ bias,
                 float* __restrict__ C, int M, int N, int K) {
    __shared__ unsigned short lds[2][2][GBM * GBK];   // 128 KiB
    char* ldsb = (char*)&lds[0][0][0];

    const size_t KB2 = (size_t)K * 2;     // bytes per logical row
    const int KT = K / GBK;

    // bijective XCD swizzle (grid % 8 == 0 guaranteed by dispatch guard)
    const int nwg = gridDim.x;
    const int b   = blockIdx.x;
    const int wg  = (b & 7) * (nwg >> 3) + (b >> 3);
    const int MT  = M / GBM;
    const int tm  = wg % MT;
    const int tn  = wg / MT;

    const int t     = threadIdx.x;
    const int lane  = t & 63;
    const int wid   = t >> 6;       // 0..7
    const int wm    = wid >> 2;     // 0..1  (128-row half)
    const int wn    = wid & 3;      // 0..3  (64-col slice)
    const int l31   = lane & 31;
    const int h16   = (lane >> 5) * 16;     // k-half byte offset
    const int swz   = (lane & 7) << 4;      // T2 read swizzle (row&7 == lane&7)
    const int lrow  = lane >> 3;            // staging row-within-8
    const int lcb   = (lane & 7) ^ lrow;    // inverse-swizzled source block

    // ---- precomputed 32-bit LDS read offsets ----
    int aoffK[4], boffK[4];
    #pragma unroll
    for (int ks = 0; ks < 4; ++ks) {
        const int colb = (ks * 32 + h16) ^ swz;
        aoffK[ks] = (wm * 128 + l31) * 128 + colb;
        boffK[ks] = (wn * 64  + l31) * 128 + colb;
    }
    const int sdst = wid * 1024 + lane * 16;        // staging dest offset

    // ---- global staging base pointers ----
    const uint8_t* gA = (const uint8_t*)A +
        ((size_t)tm * GBM + wid * 8 + lrow) * KB2 + (size_t)lcb * 16;
    const uint8_t* gB = (const uint8_t*)Bw +
        ((size_t)tn * GBN + wid * 8 + lrow) * KB2 + (size_t)lcb * 16;

    f32x16 acc[4][2] = {};
    bf16x8 Af[2][4], B0[4], B1[4];

    // ---- prologue: stage tiles 0 (parity 0) and 1 (parity 1) ----
    STAGE_(gB, (size_t)0,   ldsb + 32768);
    STAGE_(gA, (size_t)0,   ldsb);
    STAGE_(gB, (size_t)128, ldsb + 65536 + 32768);
    STAGE_(gA, (size_t)128, ldsb + 65536);
    asm volatile("s_waitcnt vmcnt(8)" ::: "memory");   // tile 0 landed
    __builtin_amdgcn_s_barrier();

    for (int kt = 0; kt < KT; ++kt) {
        const int coff = (kt & 1) << 16;          // 0 / 65536
        const char* ldsA = ldsb + coff;
        const char* ldsB = ldsb + coff + 32768;
        char* ldsAw = (char*)ldsA;                // kt+2 shares parity with kt
        char* ldsBw = (char*)ldsB;
        const bool more = (kt + 2) < KT;
        const size_t kb2 = (size_t)(kt + 2) * 128;

        // ---- P1: A(qm0)+B(nt0) reads; MFMA (qm0, nt0) ----
        LDA_(0);
        LDB_(0, B0);
        PH_IN();  MFMA_(0, 0, B0);  PH_OUT();

        // ---- P2: B(nt1) reads; MFMA (qm0, nt1) ----
        LDB_(1, B1);
        PH_IN();  MFMA_(0, 1, B1);  PH_OUT();

        // ---- P3: A(qm1) reads; stage B(kt+2) (B dead since P2-out); MFMA (qm1, nt1) ----
        LDA_(1);
        if (more) STAGE_(gB, kb2, ldsBw);
        PH_IN();  MFMA_(1, 1, B1);  PH_OUT();

        // ---- P4: stage A(kt+2) (A dead since P3-out); MFMA (qm1, nt0) from regs ----
        if (more) STAGE_(gA, kb2, ldsAw);
        __builtin_amdgcn_s_setprio(1);
        MFMA_(1, 0, B0);
        __builtin_amdgcn_s_setprio(0);
        if (more) asm volatile("s_waitcnt vmcnt(8)" ::: "memory"); // kt+1 landed
        else      asm volatile("s_waitcnt vmcnt(0)" ::: "memory"); // drain
        __builtin_amdgcn_s_barrier();
    }

    // ---- epilogue: 32x32 C/D layout col=lane&31, row=(r&3)+8*(r>>2)+4*(lane>>5) ----
    const float inv = *invp;
    const int h5 = lane >> 5;
    const float bv0 = bias[tn * GBN + wn * 64 + l31];
    const float bv1 = bias[tn * GBN + wn * 64 + 32 + l31];

    #pragma unroll
    for (int mt = 0; mt < 4; ++mt) {
        const int rowb = tm * GBM + wm * 128 + mt * 32 + h5 * 4;
        #pragma unroll
        for (int r = 0; r < 16; ++r) {
            const int row = rowb + (r & 3) + 8 * (r >> 2);
            float* cp = C + (size_t)row * N + tn * GBN + wn * 64 + l31;
            cp[0]  = acc[mt][0][r] * inv + bv0;
            cp[32] = acc[mt][1][r] * inv + bv1;
        }
    }
}

// ---------- fallback (insurance, mode-aware) ----------
__global__ void naive_kernel(const float* __restrict__ x,
                             const void* __restrict__ wsrc,
                             const uint32_t* flag,
                             const float* __restrict__ invp,
                             const float* __restrict__ bias,
                             float* __restrict__ out, int M, int N, int K) {
    const uint32_t mode = flag ? *flag : 0u;
    size_t idx = (size_t)blockIdx.x * blockDim.x + threadIdx.x;
    if (idx >= (size_t)M * N) return;
    int m = (int)(idx / N), n = (int)(idx % N);
    const float* xr = x + (size_t)m * K;
    float s = 0.f;
    if (mode == 0) {
        const float* wr = (const float*)wsrc + (size_t)n * K;
        for (int k = 0; k < K; ++k) s += xr[k] * wr[k];
    } else if (mode == 1) {
        const unsigned short* wr = (const unsigned short*)wsrc + (size_t)n * K;
        for (int k = 0; k < K; ++k)
            s += xr[k] * __uint_as_float(((uint32_t)wr[k]) << 16);
    } else {
        const uint8_t* wr = (const uint8_t*)wsrc + (size_t)n * K;
        for (int k = 0; k < K; ++k) s += xr[k] * fp8e4m3_to_f32(wr[k]);
    }
    out[idx] = s * (*invp) + bias[n];
}

extern "C" void kernel_launch(void* const* d_in, const int* in_sizes, int n_in,
                              void* d_out, int out_size, void* d_ws, size_t ws_size,
                              hipStream_t stream) {
    const float*    x    = (const float*)d_in[0];
    const void*     wsrc = d_in[1];
    const float*    inv  = (const float*)d_in[2];
    const float*    bias = (const float*)d_in[3];
    float*          out  = (float*)d_out;

    const int K = in_sizes[1] / in_sizes[3];   // D_IN  = 4096
    const int N = in_sizes[3];                 // D_OUT = 4096
    const int M = in_sizes[0] / K;             // B*S   = 8192

    const size_t needA = (size_t)M * K * sizeof(unsigned short);
    const size_t needB = (size_t)N * K * sizeof(unsigned short);

    const bool shape_ok = (M % GBM) == 0 && (N % GBN) == 0 && (K % GBK) == 0 &&
                          (K / GBK) >= 2 &&
                          (((M / GBM) * (N / GBN)) % 8) == 0;

    if (ws_size < needA + needB + 256 || !shape_ok) {
        size_t total = (size_t)M * N;
        uint32_t* flag = (ws_size >= 256) ? (uint32_t*)d_ws : nullptr;
        if (flag) detect_kernel<<<1, 256, 0, stream>>>((const uint32_t*)wsrc, flag);
        naive_kernel<<<(unsigned)((total + 255) / 256), 256, 0, stream>>>(
            x, wsrc, flag, inv, bias, out, M, N, K);
        return;
    }

    uint32_t*       flag = (uint32_t*)d_ws;
    unsigned short* Abf  = (unsigned short*)((char*)d_ws + 256);
    unsigned short* Wbf  = (unsigned short*)((char*)d_ws + 256 + needA);

    detect_kernel<<<1, 256, 0, stream>>>((const uint32_t*)wsrc, flag);
    cvt_x_kernel<<<2048, 256, 0, stream>>>(x, Abf, (size_t)M * K / 8);
    prep_w_kernel<<<2048, 256, 0, stream>>>(wsrc, flag, Wbf, (size_t)N * K / 8);

    dim3 grid((M / GBM) * (N / GBN));
    gemm256_8ph<<<grid, 512, 0, stream>>>(Abf, Wbf, inv, bias, out, M, N, K);
}

// Round 8
// 297.401 us; speedup vs baseline: 1.0972x; 1.0972x over previous
//
#include <hip/hip_runtime.h>
#include <hip/hip_bf16.h>
#include <stdint.h>
#include <stddef.h>

// ---------- types ----------
typedef __bf16 bf16x8 __attribute__((ext_vector_type(8)));
typedef float  f32x4  __attribute__((ext_vector_type(4)));

// ---------- helpers ----------
__device__ __forceinline__ float fp8e4m3_to_f32(uint32_t b) {
    uint32_t e = (b >> 3) & 15u, m = b & 7u;
    float mag;
    if (e == 0)
        mag = (float)m * (1.0f / 512.0f);
    else
        mag = __uint_as_float(((e + 120u) << 23) | (m << 20));
    return (b & 0x80u) ? -mag : mag;
}

__device__ __forceinline__ unsigned short f32_to_bf16_bits(float f) {
    uint32_t x = __float_as_uint(f);
    uint32_t r = x + 0x7fffu + ((x >> 16) & 1u);   // RNE
    return (unsigned short)(r >> 16);
}

__device__ __forceinline__ void gload_lds16(const void* g, void* l) {
    __builtin_amdgcn_global_load_lds(
        (const __attribute__((address_space(1))) uint32_t*)g,
        (__attribute__((address_space(3))) uint32_t*)l,
        16, 0, 0);
}

// ---------- dtype detector (3-way), validated round 3 (mode 0 = f32) ----------
__global__ void detect_kernel(const uint32_t* __restrict__ w,
                              uint32_t* __restrict__ flag) {
    __shared__ int sF, sB;
    if (threadIdx.x == 0) { sF = 1; sB = 1; }
    __syncthreads();
    int f32ok = 1, bf16ok = 1;
    #pragma unroll
    for (int i = 0; i < 16; ++i) {
        uint32_t u = w[threadIdx.x * 16 + i];
        if (u & 0x000FFFFFu) f32ok = 0;
        if (u & 0x000F000Fu) bf16ok = 0;
    }
    if (!f32ok)  atomicExch(&sF, 0);
    if (!bf16ok) atomicExch(&sB, 0);
    __syncthreads();
    if (threadIdx.x == 0)
        *flag = sF ? 0u : (sB ? 1u : 2u);
}

// ---------- pre-pass 1: x f32 -> bf16 ----------
__global__ void cvt_x_kernel(const float* __restrict__ x,
                             unsigned short* __restrict__ out, size_t n8) {
    size_t stride = (size_t)gridDim.x * blockDim.x;
    for (size_t i = (size_t)blockIdx.x * blockDim.x + threadIdx.x; i < n8; i += stride) {
        const float4* p = (const float4*)(x + i * 8);
        float4 a = p[0], b = p[1];
        union { uint4 v; unsigned short s[8]; } o;
        o.s[0] = f32_to_bf16_bits(a.x); o.s[1] = f32_to_bf16_bits(a.y);
        o.s[2] = f32_to_bf16_bits(a.z); o.s[3] = f32_to_bf16_bits(a.w);
        o.s[4] = f32_to_bf16_bits(b.x); o.s[5] = f32_to_bf16_bits(b.y);
        o.s[6] = f32_to_bf16_bits(b.z); o.s[7] = f32_to_bf16_bits(b.w);
        *(uint4*)(out + i * 8) = o.v;
    }
}

// ---------- pre-pass 2: weight (any mode) -> canonical bf16 ----------
__global__ void prep_w_kernel(const void* __restrict__ wsrc,
                              const uint32_t* __restrict__ flag,
                              unsigned short* __restrict__ out, size_t n8) {
    const uint32_t mode = *flag;
    size_t stride = (size_t)gridDim.x * blockDim.x;
    for (size_t i = (size_t)blockIdx.x * blockDim.x + threadIdx.x; i < n8; i += stride) {
        union { uint4 v; unsigned short s[8]; } o;
        if (mode == 0) {
            const float4* p = (const float4*)((const float*)wsrc + i * 8);
            float4 a = p[0], b = p[1];
            o.s[0] = f32_to_bf16_bits(a.x); o.s[1] = f32_to_bf16_bits(a.y);
            o.s[2] = f32_to_bf16_bits(a.z); o.s[3] = f32_to_bf16_bits(a.w);
            o.s[4] = f32_to_bf16_bits(b.x); o.s[5] = f32_to_bf16_bits(b.y);
            o.s[6] = f32_to_bf16_bits(b.z); o.s[7] = f32_to_bf16_bits(b.w);
        } else if (mode == 1) {
            o.v = *(const uint4*)((const unsigned short*)wsrc + i * 8);
        } else {
            union { uint2 v; uint8_t b[8]; } u;
            u.v = *(const uint2*)((const uint8_t*)wsrc + i * 8);
            #pragma unroll
            for (int j = 0; j < 8; ++j)
                o.s[j] = f32_to_bf16_bits(fp8e4m3_to_f32(u.b[j]));
        }
        *(uint4*)(out + i * 8) = o.v;
    }
}

// ================= 256x256 GEMM, 16x16x32 MFMA, 2-barrier free-run ==========
// Round-8 delta vs round-6: shape reverted to 16x16x32 (conflict-free,
// verified r4-r6); phase barriers collapsed 7 -> 2 per K-tile so the
// block's 8 waves FREE-RUN within two windows and LDS read service (196
// KB/K-tile, ~766 cyc at 256 B/cyc) hides under the MFMA pipe (2048 cyc
// floor) instead of serializing with it (lockstep cost: 4988 cyc measured).
// Hazard inventory:
//   - reads(kt) vs stage(kt+2) same-parity WAR: per-wave lgkmcnt(0) +
//     barrier #1 -> all waves' reads drained before any wave stages.
//   - stage(kt+1) completion before reads(kt+1): per-wave vmcnt(8) +
//     barrier #2 (same as r4-r6, validated).
//   - gload_lds increments vmcnt only, so lgkmcnt(0) waits ds_reads only.

#define GBM 256
#define GBN 256
#define GBK 64

#define LDA_(qm) do {                                                          \
    _Pragma("unroll") for (int m = 0; m < 4; ++m) {                            \
        Af[m][0] = *(const bf16x8*)(a0 + ((qm)*8192 + m*2048));                \
        Af[m][1] = *(const bf16x8*)(a1 + ((qm)*8192 + m*2048));                \
    }                                                                          \
} while (0)

#define LDB_(qn, Bf) do {                                                      \
    _Pragma("unroll") for (int n = 0; n < 2; ++n) {                            \
        Bf[n][0] = *(const bf16x8*)(b0 + ((qn)*4096 + n*2048));                \
        Bf[n][1] = *(const bf16x8*)(b1 + ((qn)*4096 + n*2048));                \
    }                                                                          \
} while (0)

#define MFMA_(qm, qn, Bf) do {                                                 \
    _Pragma("unroll") for (int m = 0; m < 4; ++m)                              \
    _Pragma("unroll") for (int n = 0; n < 2; ++n)                              \
    _Pragma("unroll") for (int ks = 0; ks < 2; ++ks)                           \
        acc[(qm)*4+m][(qn)*2+n] = __builtin_amdgcn_mfma_f32_16x16x32_bf16(     \
            Af[m][ks], Bf[n][ks], acc[(qm)*4+m][(qn)*2+n], 0, 0, 0);           \
} while (0)

#define STAGE_(gsrc, koff, ldst) do {                                          \
    const uint8_t* _p = (gsrc) + (koff);                                       \
    _Pragma("unroll") for (int j = 0; j < 4; ++j)                              \
        gload_lds16(_p + (size_t)j * 64 * KB2, (ldst) + (sdst + j*8192));      \
} while (0)

__global__ __launch_bounds__(512, 2)
void gemm256_fr(const unsigned short* __restrict__ A,
                const unsigned short* __restrict__ Bw,
                const float* __restrict__ invp,
                const float* __restrict__ bias,
                float* __restrict__ C, int M, int N, int K) {
    __shared__ unsigned short lds[2][2][GBM * GBK];   // 128 KiB
    char* ldsb = (char*)&lds[0][0][0];

    const size_t KB2 = (size_t)K * 2;     // bytes per logical row
    const int KT = K / GBK;

    // bijective XCD swizzle (grid % 8 == 0 guaranteed by dispatch guard)
    const int nwg = gridDim.x;
    const int b   = blockIdx.x;
    const int wg  = (b & 7) * (nwg >> 3) + (b >> 3);
    const int MT  = M / GBM;
    const int tm  = wg % MT;
    const int tn  = wg / MT;

    const int t     = threadIdx.x;
    const int lane  = t & 63;
    const int wid   = t >> 6;       // 0..7
    const int wm    = wid >> 2;     // 0..1
    const int wn    = wid & 3;      // 0..3
    const int laneQ = lane & 15;
    const int laneH = lane >> 4;
    const int xorv  = (laneQ & 7) << 4;     // T2 read swizzle
    const int lrow  = lane >> 3;            // staging row-within-8
    const int lcb   = (lane & 7) ^ lrow;    // inverse-swizzled source block

    // ---- precomputed 32-bit LDS read offsets ----
    const int col0  = (0   + laneH * 16) ^ xorv;
    const int col1  = (64  + laneH * 16) ^ xorv;
    const int aoff0 = wm * 16384 + laneQ * 128 + col0;
    const int aoff1 = wm * 16384 + laneQ * 128 + col1;
    const int boff0 = wn * 8192  + laneQ * 128 + col0;
    const int boff1 = wn * 8192  + laneQ * 128 + col1;
    const int sdst  = wid * 1024 + lane * 16;        // staging dest offset

    // ---- global staging base pointers ----
    const uint8_t* gA = (const uint8_t*)A +
        ((size_t)tm * GBM + wid * 8 + lrow) * KB2 + (size_t)lcb * 16;
    const uint8_t* gB = (const uint8_t*)Bw +
        ((size_t)tn * GBN + wid * 8 + lrow) * KB2 + (size_t)lcb * 16;

    f32x4 acc[8][4] = {};
    bf16x8 Af[4][2], B0[2][2], B1[2][2];

    // ---- prologue: stage tiles 0 (parity 0) and 1 (parity 1) ----
    STAGE_(gB, (size_t)0,   ldsb + 32768);
    STAGE_(gA, (size_t)0,   ldsb);
    STAGE_(gB, (size_t)128, ldsb + 65536 + 32768);
    STAGE_(gA, (size_t)128, ldsb + 65536);
    asm volatile("s_waitcnt vmcnt(8)" ::: "memory");   // tile 0 landed
    __builtin_amdgcn_s_barrier();

    for (int kt = 0; kt < KT; ++kt) {
        const int coff = (kt & 1) << 16;          // 0 / 65536
        const char* ldsA = ldsb + coff;
        const char* ldsB = ldsb + coff + 32768;
        const char* a0 = ldsA + aoff0;
        const char* a1 = ldsA + aoff1;
        const char* b0 = ldsB + boff0;
        const char* b1 = ldsB + boff1;
        char* ldsAw = (char*)ldsA;                // kt+2 shares parity with kt
        char* ldsBw = (char*)ldsB;
        const bool more = (kt + 2) < KT;
        const size_t kb2 = (size_t)(kt + 2) * 128;

        // ===== window A (free-run): all 24 reads + 2 MFMA quadrants =====
        LDA_(0);
        LDB_(0, B0);
        __builtin_amdgcn_s_setprio(1);
        MFMA_(0, 0, B0);
        __builtin_amdgcn_s_setprio(0);
        LDB_(1, B1);
        __builtin_amdgcn_s_setprio(1);
        MFMA_(0, 1, B1);
        __builtin_amdgcn_s_setprio(0);
        LDA_(1);
        asm volatile("s_waitcnt lgkmcnt(0)" ::: "memory");  // own reads drained
        __builtin_amdgcn_s_barrier();   // #1: ALL waves' reads of tile kt done

        // ===== window B: stage kt+2 (dead region), remaining 2 quadrants ====
        if (more) {
            STAGE_(gB, kb2, ldsBw);
            STAGE_(gA, kb2, ldsAw);
        }
        __builtin_amdgcn_s_setprio(1);
        MFMA_(1, 1, B1);
        MFMA_(1, 0, B0);
        __builtin_amdgcn_s_setprio(0);
        if (more) asm volatile("s_waitcnt vmcnt(8)" ::: "memory"); // kt+1 landed
        else      asm volatile("s_waitcnt vmcnt(0)" ::: "memory"); // drain
        __builtin_amdgcn_s_barrier();   // #2: next parity ready
    }

    // ---- epilogue: C/D layout col=laneQ, row=laneH*4+reg [m89-verified] ----
    const float inv = *invp;
    float bv[4];
    #pragma unroll
    for (int n = 0; n < 4; ++n)
        bv[n] = bias[tn * GBN + wn * 64 + n * 16 + laneQ];

    #pragma unroll
    for (int m = 0; m < 8; ++m) {
        int rowb = tm * GBM + wm * 128 + m * 16 + laneH * 4;
        #pragma unroll
        for (int j = 0; j < 4; ++j) {
            float* cp = C + (size_t)(rowb + j) * N + tn * GBN + wn * 64;
            #pragma unroll
            for (int n = 0; n < 4; ++n)
                cp[n * 16 + laneQ] = acc[m][n][j] * inv + bv[n];
        }
    }
}

// ---------- fallback (insurance, mode-aware) ----------
__global__ void naive_kernel(const float* __restrict__ x,
                             const void* __restrict__ wsrc,
                             const uint32_t* flag,
                             const float* __restrict__ invp,
                             const float* __restrict__ bias,
                             float* __restrict__ out, int M, int N, int K) {
    const uint32_t mode = flag ? *flag : 0u;
    size_t idx = (size_t)blockIdx.x * blockDim.x + threadIdx.x;
    if (idx >= (size_t)M * N) return;
    int m = (int)(idx / N), n = (int)(idx % N);
    const float* xr = x + (size_t)m * K;
    float s = 0.f;
    if (mode == 0) {
        const float* wr = (const float*)wsrc + (size_t)n * K;
        for (int k = 0; k < K; ++k) s += xr[k] * wr[k];
    } else if (mode == 1) {
        const unsigned short* wr = (const unsigned short*)wsrc + (size_t)n * K;
        for (int k = 0; k < K; ++k)
            s += xr[k] * __uint_as_float(((uint32_t)wr[k]) << 16);
    } else {
        const uint8_t* wr = (const uint8_t*)wsrc + (size_t)n * K;
        for (int k = 0; k < K; ++k) s += xr[k] * fp8e4m3_to_f32(wr[k]);
    }
    out[idx] = s * (*invp) + bias[n];
}

extern "C" void kernel_launch(void* const* d_in, const int* in_sizes, int n_in,
                              void* d_out, int out_size, void* d_ws, size_t ws_size,
                              hipStream_t stream) {
    const float*    x    = (const float*)d_in[0];
    const void*     wsrc = d_in[1];
    const float*    inv  = (const float*)d_in[2];
    const float*    bias = (const float*)d_in[3];
    float*          out  = (float*)d_out;

    const int K = in_sizes[1] / in_sizes[3];   // D_IN  = 4096
    const int N = in_sizes[3];                 // D_OUT = 4096
    const int M = in_sizes[0] / K;             // B*S   = 8192

    const size_t needA = (size_t)M * K * sizeof(unsigned short);
    const size_t needB = (size_t)N * K * sizeof(unsigned short);

    const bool shape_ok = (M % GBM) == 0 && (N % GBN) == 0 && (K % GBK) == 0 &&
                          (K / GBK) >= 2 &&
                          (((M / GBM) * (N / GBN)) % 8) == 0;

    if (ws_size < needA + needB + 256 || !shape_ok) {
        size_t total = (size_t)M * N;
        uint32_t* flag = (ws_size >= 256) ? (uint32_t*)d_ws : nullptr;
        if (flag) detect_kernel<<<1, 256, 0, stream>>>((const uint32_t*)wsrc, flag);
        naive_kernel<<<(unsigned)((total + 255) / 256), 256, 0, stream>>>(
            x, wsrc, flag, inv, bias, out, M, N, K);
        return;
    }

    uint32_t*       flag = (uint32_t*)d_ws;
    unsigned short* Abf  = (unsigned short*)((char*)d_ws + 256);
    unsigned short* Wbf  = (unsigned short*)((char*)d_ws + 256 + needA);

    detect_kernel<<<1, 256, 0, stream>>>((const uint32_t*)wsrc, flag);
    cvt_x_kernel<<<2048, 256, 0, stream>>>(x, Abf, (size_t)M * K / 8);
    prep_w_kernel<<<2048, 256, 0, stream>>>(wsrc, flag, Wbf, (size_t)N * K / 8);

    dim3 grid((M / GBM) * (N / GBN));
    gemm256_fr<<<grid, 512, 0, stream>>>(Abf, Wbf, inv, bias, out, M, N, K);
}